// Round 10
// baseline (204.818 us; speedup 1.0000x reference)
//
#include <hip/hip_runtime.h>
#include <hip/hip_bf16.h>
#include <math.h>

// Problem constants
#define Bb 4
#define Ss 2048
#define Hh 1024
#define Ff 513           // H/2 + 1 rfft bins
#define FEAT 1026        // cos||sin feature length
#define KP2 1088         // padded feature K (17 * 64)

typedef __attribute__((ext_vector_type(8))) short bf16x8;
typedef __attribute__((ext_vector_type(4))) float f32x4;
typedef __attribute__((ext_vector_type(16))) float f32x16;

typedef const __attribute__((address_space(1))) void GVoid;
typedef __attribute__((address_space(3))) void LVoid;

// padded LDS index for float2 arrays: breaks power-of-2 stride conflicts
#define PADI(i) ((i) + ((i) >> 4))

__device__ __forceinline__ float2 cmul(float2 a, float2 b) {
  return make_float2(a.x * b.x - a.y * b.y, a.x * b.y + a.y * b.x);
}

__device__ __forceinline__ unsigned short bf16bits(float x) {
  __hip_bfloat16 h = __float2bfloat16(x);
  return *reinterpret_cast<unsigned short*>(&h);
}

// Inline-asm LDS read: opaque to compiler waitcnt insertion (round-6 win).
// Ordering is manual: s_waitcnt lgkmcnt(0) + sched_barrier(0) before each
// MFMA cluster (rule #18), barriers between phases.
__device__ __forceinline__ bf16x8 lds_read_b128(const short* p) {
  bf16x8 r;
  asm volatile("ds_read_b128 %0, %1"
               : "=&v"(r)
               : "v"((const __attribute__((address_space(3))) short*)p));
  return r;
}

// ---------------------------------------------------------------------------
// Kernel 1: packed-real FFT. One block per (b,s) row-pair: z = Q_row + i*K_row,
// single 1024-pt radix-4 DIT FFT (5 stages), untangle, unit-normalize,
// emit bf16 [cos||sin] features.
// ---------------------------------------------------------------------------
__global__ __launch_bounds__(256) void fft_phase_kernel(
    const float* __restrict__ Q, const float* __restrict__ Kin,
    __hip_bfloat16* __restrict__ FQ, __hip_bfloat16* __restrict__ FK) {
  const int row = blockIdx.x;                     // 0 .. B*S-1
  const float* qs = Q   + (size_t)row * Hh;
  const float* ks = Kin + (size_t)row * Hh;
  __hip_bfloat16* fq = FQ + (size_t)row * KP2;
  __hip_bfloat16* fk = FK + (size_t)row * KP2;

  __shared__ float2 data[PADI(1023) + 1];
  __shared__ float2 tw[1024];
  const int tid = threadIdx.x;

#pragma unroll
  for (int e = 0; e < 4; ++e) {
    const int m = tid + e * 256;
    float s, c;
    sincosf(-6.283185307179586f * (float)m * (1.0f / 1024.0f), &s, &c);
    tw[m] = make_float2(c, s);
  }
#pragma unroll
  for (int e = 0; e < 4; ++e) {
    const int n = tid + e * 256;
    const int r4 = ((n & 3) << 8) | (((n >> 2) & 3) << 6) | (((n >> 4) & 3) << 4)
                 | (((n >> 6) & 3) << 2) | ((n >> 8) & 3);
    data[PADI(r4)] = make_float2(qs[n], ks[n]);
  }
  __syncthreads();

  int quarter = 1, step = 256;
  for (int s = 0; s < 5; ++s) {
    const int j = tid & (quarter - 1);
    const int pos = 4 * tid - 3 * j;
    const float2 x0 = data[PADI(pos)];
    const float2 x1 = data[PADI(pos + quarter)];
    const float2 x2 = data[PADI(pos + 2 * quarter)];
    const float2 x3 = data[PADI(pos + 3 * quarter)];
    const int e1 = j * step;
    const float2 a1 = cmul(x1, tw[e1]);
    const float2 a2 = cmul(x2, tw[2 * e1]);
    const float2 a3 = cmul(x3, tw[3 * e1]);
    const float2 t0 = make_float2(x0.x + a2.x, x0.y + a2.y);
    const float2 t1 = make_float2(x0.x - a2.x, x0.y - a2.y);
    const float2 t2 = make_float2(a1.x + a3.x, a1.y + a3.y);
    const float2 t3 = make_float2(a1.x - a3.x, a1.y - a3.y);
    data[PADI(pos)]               = make_float2(t0.x + t2.x, t0.y + t2.y);
    data[PADI(pos + quarter)]     = make_float2(t1.x + t3.y, t1.y - t3.x);
    data[PADI(pos + 2 * quarter)] = make_float2(t0.x - t2.x, t0.y - t2.y);
    data[PADI(pos + 3 * quarter)] = make_float2(t1.x - t3.y, t1.y + t3.x);
    __syncthreads();
    quarter <<= 2; step >>= 2;
  }

  for (int f = tid; f <= 512; f += 256) {
    const float2 z1 = data[PADI(f)];
    const float2 z2 = data[PADI((1024 - f) & 1023)];
    const float qr = z1.x + z2.x, qi = z1.y - z2.y;
    const float kr = z1.y + z2.y, ki = z2.x - z1.x;
    float qc, qsn, kc, ksn;
    const float qm2 = qr * qr + qi * qi;
    if (qm2 > 1e-30f) { const float iv = rsqrtf(qm2); qc = qr * iv; qsn = qi * iv; }
    else              { qc = 1.0f; qsn = 0.0f; }
    const float km2 = kr * kr + ki * ki;
    if (km2 > 1e-30f) { const float iv = rsqrtf(km2); kc = kr * iv; ksn = ki * iv; }
    else              { kc = 1.0f; ksn = 0.0f; }
    fq[f] = __float2bfloat16(qc); fq[Ff + f] = __float2bfloat16(qsn);
    fk[f] = __float2bfloat16(kc); fk[Ff + f] = __float2bfloat16(ksn);
  }
  for (int p = FEAT + tid; p < KP2; p += 256) {
    fq[p] = __float2bfloat16(0.0f);
    fk[p] = __float2bfloat16(0.0f);
  }
}

// ---------------------------------------------------------------------------
// Kernel 2: V [B,S,H] fp32 -> Vt [B,H,S] bf16 (transpose, LDS 32x33 tile)
// ---------------------------------------------------------------------------
__global__ __launch_bounds__(256) void vt_kernel(
    const float* __restrict__ V, __hip_bfloat16* __restrict__ Vt) {
  const int b = blockIdx.z;
  const int h0 = blockIdx.x * 32;
  const int s0 = blockIdx.y * 32;
  __shared__ float t[32][33];
  const int tid = threadIdx.x;
  const int c = tid & 31;
  const int r8 = tid >> 5;
  const float* Vb = V + (size_t)b * Ss * Hh;
#pragma unroll
  for (int e = 0; e < 4; ++e) {
    const int r = r8 + e * 8;
    t[r][c] = Vb[(size_t)(s0 + r) * Hh + h0 + c];
  }
  __syncthreads();
  __hip_bfloat16* O = Vt + (size_t)b * Hh * Ss;
#pragma unroll
  for (int e = 0; e < 4; ++e) {
    const int hh = r8 + e * 8;
    O[(size_t)(h0 + hh) * Ss + s0 + c] = __float2bfloat16(t[c][hh]);
  }
}

// ---------------------------------------------------------------------------
// bf16 MFMA GEMM (32x32x16), C = A * B^T, 128x128 tile, BK=64, 8 waves
// (2M x 4N; wave tile 64x32), 2 phases per K-tile, counted vmcnt.
// ROUND-10 CHANGE: 64 KB LDS -> 2 WGs/CU co-resident (round-9 post-mortem:
// at 96-128 KB = 1 WG/CU, all 8 waves are phase-lockstep and MfmaUtil ==
// exactly the single-WG MFMA/phase arithmetic (22%) -> pipes idle between
// phases with nothing to fill them. m97's 874 TF had ~3 WGs/CU; overlap
// comes from co-resident WGs, not intra-WG schedule shape — which rounds
// 7-9 proved neutral).
// Staging: chunk (kh) = A 8KB + B 8KB = 1+1 loads/wave. Deep wait vmcnt(4)
// = 2 chunk-pairs in flight -> chunk needed next phase landed (issued 2
// phases ago). WAR: each stage >= 1 barrier after its region's last read.
// LDS layout per buffer: [rg][kc][512 shorts] 1KB subtiles; linear
// global_load_lds lane write == ds_read order == MFMA operand order
// (row=lane&31, k8=lane>>5) -> conflict-free, swizzle-free.
// C/D layout [m74/m101]: col=lane&31, row=(reg&3)+8*(reg>>2)+4*(lane>>5).
// EPI 0: C = acc/513 (scores; +1 dropped, softmax shift-invariant).
// EPI 1: C = acc (PV).
// ---------------------------------------------------------------------------
template<int K, int LDA, int LDB, int LDC, int EPI>
__global__ __launch_bounds__(512, 4) void gemm32(
    const __hip_bfloat16* __restrict__ Ag, const __hip_bfloat16* __restrict__ Bg,
    float* __restrict__ Cg, size_t strA, size_t strB, size_t strC) {
  constexpr int nt = K / 64;
  constexpr int MF = 2;           // m-frags per wave (2 x 32 = 64 rows)

  // bijective XCD swizzle: consecutive processed tiles land on one XCD's L2
  const int gx = gridDim.x, gy = gridDim.y;
  const int nwg = gx * gy * (int)gridDim.z;
  int f = ((int)blockIdx.z * gy + (int)blockIdx.y) * gx + (int)blockIdx.x;
  f = (f & 7) * (nwg >> 3) + (f >> 3);
  const int bx = f % gx; f /= gx;
  const int by = f % gy;
  const int bz = f / gy;

  const int i0 = by * 128;
  const int j0 = bx * 128;
  const char* Ab = (const char*)(Ag + (size_t)bz * strA);
  const char* Bp = (const char*)(Bg + (size_t)bz * strB);
  float* C = Cg + (size_t)bz * strC;

  __shared__ short As[2][8192];   // 2 x 16KB  ([rg 0..3][kc 0..3][512])
  __shared__ short Bs[2][8192];   // 2 x 16KB   -> 64KB total: 2 WGs/CU

  const int tid = threadIdx.x;
  const int lane = tid & 63;
  const int w  = tid >> 6;        // wave 0..7
  const int wm = w >> 2;          // 0..1 (M: 64 rows each)
  const int wn = w & 3;           // 0..3 (N: 32 cols each)

  f32x16 acc[MF];
#pragma unroll
  for (int mi = 0; mi < MF; ++mi)
#pragma unroll
    for (int r = 0; r < 16; ++r) acc[mi][r] = 0.0f;

#define BAR() __builtin_amdgcn_s_barrier()
  // deep wait: 2 chunk-pairs (A+B) in flight = 4 loads
#define WAITDEEP() asm volatile("s_waitcnt vmcnt(4)")

  // stage A/B chunk (khalf kh = 2 k-chunks of 16) of K-tile tt into buffer dd
  // one load per wave each: wave w covers subtile rg = w>>1, kc = 2*kh+(w&1)
#define SA(dd, tt, kh)                                                                   \
  do {                                                                                   \
    const int rg_ = w >> 1;                                                              \
    const int kc_ = 2 * (kh) + (w & 1);                                                  \
    __builtin_amdgcn_global_load_lds(                                                    \
        (GVoid*)(Ab + (size_t)(i0 + rg_ * 32 + (lane & 31)) * (LDA * 2) +                \
                 (size_t)(tt) * 128 + kc_ * 32 + (lane >> 5) * 16),                      \
        (LVoid*)&As[dd][(rg_ * 4 + kc_) * 512], 16, 0, 0);                               \
  } while (0)
#define SB(dd, tt, kh)                                                                   \
  do {                                                                                   \
    const int rg_ = w >> 1;                                                              \
    const int kc_ = 2 * (kh) + (w & 1);                                                  \
    __builtin_amdgcn_global_load_lds(                                                    \
        (GVoid*)(Bp + (size_t)(j0 + rg_ * 32 + (lane & 31)) * (LDB * 2) +                \
                 (size_t)(tt) * 128 + kc_ * 32 + (lane >> 5) * 16),                      \
        (LVoid*)&Bs[dd][(rg_ * 4 + kc_) * 512], 16, 0, 0);                               \
  } while (0)
  // read m-frags / n-frag (k-half kh) via asm ds_read
#define RA(dd, kh)                                                                       \
  _Pragma("unroll")                                                                      \
  for (int mi = 0; mi < MF; ++mi)                                                        \
    _Pragma("unroll")                                                                    \
    for (int kb = 0; kb < 2; ++kb)                                                       \
      af[mi][kb] = lds_read_b128(                                                        \
          &As[dd][((wm * MF + mi) * 4 + 2 * (kh) + kb) * 512 + lane * 8]);
#define RB(dd, kh)                                                                       \
  _Pragma("unroll")                                                                      \
  for (int kb = 0; kb < 2; ++kb)                                                         \
    bf[kb] = lds_read_b128(                                                              \
        &Bs[dd][(wn * 4 + 2 * (kh) + kb) * 512 + lane * 8]);
#define MM()                                                                             \
  asm volatile("s_waitcnt lgkmcnt(0)");                                                  \
  __builtin_amdgcn_sched_barrier(0);                                                     \
  __builtin_amdgcn_s_setprio(1);                                                         \
  _Pragma("unroll")                                                                      \
  for (int mi = 0; mi < MF; ++mi)                                                        \
    _Pragma("unroll")                                                                    \
    for (int kb = 0; kb < 2; ++kb)                                                       \
      acc[mi] = __builtin_amdgcn_mfma_f32_32x32x16_bf16(                                 \
          af[mi][kb], bf[kb], acc[mi], 0, 0, 0);                                         \
  __builtin_amdgcn_s_setprio(0);                                                         \
  __builtin_amdgcn_sched_barrier(0);

  // prologue: (0,kh0), (0,kh1), (1,kh0); deep wait guarantees (0,kh0)
  SA(0, 0, 0); SB(0, 0, 0);
  SA(0, 0, 1); SB(0, 0, 1);
  SA(1, 1, 0); SB(1, 1, 0);
  WAITDEEP();
  BAR();

  for (int t = 0; t < nt; ++t) {
    const int d = t & 1;
    bf16x8 af[MF][2], bf[2];

    // ---- phase 0: k-half 0
    RA(d, 0); RB(d, 0);
    if (t + 1 < nt) { SA(d ^ 1, t + 1, 1); SB(d ^ 1, t + 1, 1); }
    MM();
    if (t + 2 < nt) WAITDEEP();
    else            asm volatile("s_waitcnt vmcnt(0)");
    BAR();

    // ---- phase 1: k-half 1
    RA(d, 1); RB(d, 1);
    if (t + 2 < nt) { SA(d, t + 2, 0); SB(d, t + 2, 0); }
    MM();
    if (t + 2 < nt) WAITDEEP();
    else            asm volatile("s_waitcnt vmcnt(0)");
    BAR();
  }
#undef SA
#undef SB
#undef RA
#undef RB
#undef MM
#undef WAITDEEP
#undef BAR

  // epilogue: 32x32 C/D layout [m74/m101]
  const int col = lane & 31;
  const int rbase = (lane >> 5) * 4;
#pragma unroll
  for (int mi = 0; mi < MF; ++mi) {
#pragma unroll
    for (int r = 0; r < 16; ++r) {
      const int row = (r & 3) + 8 * (r >> 2) + rbase;
      const int i = i0 + wm * 64 + mi * 32 + row;
      const int j = j0 + wn * 32 + col;
      float v = acc[mi][r];
      if (EPI == 0) v *= (1.0f / 513.0f);
      C[(size_t)i * LDC + j] = v;
    }
  }
}

// ---------------------------------------------------------------------------
// Kernel 3: in-place row softmax over 2048 cols + bf16 copy for PV GEMM.
// ---------------------------------------------------------------------------
__global__ __launch_bounds__(256) void softmax_kernel(
    float* __restrict__ W, __hip_bfloat16* __restrict__ Wb) {
  const size_t row = blockIdx.x;
  float* p = W + row * (size_t)Ss;
  __hip_bfloat16* pb = Wb + row * (size_t)Ss;
  const int tid = threadIdx.x;
  __shared__ float red[4];

  const float4* p4 = (const float4*)p;
  const float4 a = p4[2 * tid];
  const float4 bq = p4[2 * tid + 1];
  float v[8] = {a.x, a.y, a.z, a.w, bq.x, bq.y, bq.z, bq.w};

  float m = v[0];
#pragma unroll
  for (int e = 1; e < 8; ++e) m = fmaxf(m, v[e]);
#pragma unroll
  for (int off = 32; off > 0; off >>= 1) m = fmaxf(m, __shfl_xor(m, off, 64));
  if ((tid & 63) == 0) red[tid >> 6] = m;
  __syncthreads();
  m = fmaxf(fmaxf(red[0], red[1]), fmaxf(red[2], red[3]));

  float sum = 0.0f;
#pragma unroll
  for (int e = 0; e < 8; ++e) { v[e] = __expf(v[e] - m); sum += v[e]; }
#pragma unroll
  for (int off = 32; off > 0; off >>= 1) sum += __shfl_xor(sum, off, 64);
  __syncthreads();
  if ((tid & 63) == 0) red[tid >> 6] = sum;
  __syncthreads();
  sum = red[0] + red[1] + red[2] + red[3];

  const float rs = 1.0f / sum;
#pragma unroll
  for (int e = 0; e < 8; ++e) v[e] *= rs;

  float4* o4 = (float4*)p;
  o4[2 * tid]     = make_float4(v[0], v[1], v[2], v[3]);
  o4[2 * tid + 1] = make_float4(v[4], v[5], v[6], v[7]);

  bf16x8 ob;
#pragma unroll
  for (int e = 0; e < 8; ++e) ob[e] = (short)bf16bits(v[e]);
  *(bf16x8*)&pb[8 * tid] = ob;
}

// ---------------------------------------------------------------------------
extern "C" void kernel_launch(void* const* d_in, const int* in_sizes, int n_in,
                              void* d_out, int out_size, void* d_ws, size_t ws_size,
                              hipStream_t stream) {
  const float* Q = (const float*)d_in[0];
  const float* K = (const float*)d_in[1];
  const float* V = (const float*)d_in[2];

  float* out     = (float*)d_out;                       // [B,S,H]
  float* weights = out + (size_t)Bb * Ss * Hh;          // [B,S,S]

  __hip_bfloat16* FQb = (__hip_bfloat16*)d_ws;
  __hip_bfloat16* FKb = FQb + (size_t)Bb * Ss * KP2;
  __hip_bfloat16* Vtb = FKb + (size_t)Bb * Ss * KP2;
  __hip_bfloat16* Wb  = (__hip_bfloat16*)d_ws;          // aliases dead FQb/FKb

  hipLaunchKernelGGL(fft_phase_kernel, dim3(Bb * Ss), dim3(256), 0, stream,
                     Q, K, FQb, FKb);
  hipLaunchKernelGGL(vt_kernel, dim3(Hh / 32, Ss / 32, Bb), dim3(256), 0, stream,
                     V, Vtb);
  // score: 128x128 tiles, grid 16x16x4 = 1024 WGs (2 WGs/CU resident)
  hipLaunchKernelGGL((gemm32<KP2, KP2, KP2, Ss, 0>), dim3(Ss / 128, Ss / 128, Bb),
                     dim3(512), 0, stream, FQb, FKb, weights,
                     (size_t)Ss * KP2, (size_t)Ss * KP2, (size_t)Ss * Ss);
  hipLaunchKernelGGL(softmax_kernel, dim3(Bb * Ss), dim3(256), 0, stream,
                     weights, Wb);
  // PV: 128x128 tiles, grid 8x16x4 = 512 WGs (2 WGs/CU resident)
  hipLaunchKernelGGL((gemm32<Ss, Ss, Ss, Hh, 1>), dim3(Hh / 128, Ss / 128, Bb),
                     dim3(512), 0, stream, Wb, Vtb, out,
                     (size_t)Ss * Ss, (size_t)Hh * Ss, (size_t)Ss * Hh);
}

// Round 13
// 180.809 us; speedup vs baseline: 1.1328x; 1.1328x over previous
//
#include <hip/hip_runtime.h>
#include <hip/hip_bf16.h>
#include <math.h>

// Problem constants
#define Bb 4
#define Ss 2048
#define Hh 1024
#define Ff 513           // H/2 + 1 rfft bins
#define KP2 1024         // feature K: cos[0..512] ++ sin[1..511]  (sin0,sin512 == 0 exactly)

typedef __attribute__((ext_vector_type(8))) short bf16x8;
typedef __attribute__((ext_vector_type(16))) float f32x16;

typedef const __attribute__((address_space(1))) void GVoid;
typedef __attribute__((address_space(3))) void LVoid;

#define PADI(i) ((i) + ((i) >> 4))

__device__ __forceinline__ float2 cmul(float2 a, float2 b) {
  return make_float2(a.x * b.x - a.y * b.y, a.x * b.y + a.y * b.x);
}

__device__ __forceinline__ unsigned short bf16bits(float x) {
  __hip_bfloat16 h = __float2bfloat16(x);
  return *reinterpret_cast<unsigned short*>(&h);
}

// Inline-asm LDS read (round-6 win: opaque to compiler waitcnt insertion).
__device__ __forceinline__ bf16x8 lds_read_b128(const short* p) {
  bf16x8 r;
  asm volatile("ds_read_b128 %0, %1"
               : "=&v"(r)
               : "v"((const __attribute__((address_space(3))) short*)p));
  return r;
}

// ---------------------------------------------------------------------------
// Kernel 1: packed-real FFT (radix-4, z = Q + iK), untangle, unit-normalize,
// emit bf16 features [cos 0..512 | sin 1..511] (exactly 1024 dims; sin[0] and
// sin[512] are identically zero for an rfft of real input — dropped exactly).
// ---------------------------------------------------------------------------
__global__ __launch_bounds__(256) void fft_phase_kernel(
    const float* __restrict__ Q, const float* __restrict__ Kin,
    __hip_bfloat16* __restrict__ FQ, __hip_bfloat16* __restrict__ FK) {
  const int row = blockIdx.x;
  const float* qs = Q   + (size_t)row * Hh;
  const float* ks = Kin + (size_t)row * Hh;
  __hip_bfloat16* fq = FQ + (size_t)row * KP2;
  __hip_bfloat16* fk = FK + (size_t)row * KP2;

  __shared__ float2 data[PADI(1023) + 1];
  __shared__ float2 tw[1024];
  const int tid = threadIdx.x;

#pragma unroll
  for (int e = 0; e < 4; ++e) {
    const int m = tid + e * 256;
    float s, c;
    sincosf(-6.283185307179586f * (float)m * (1.0f / 1024.0f), &s, &c);
    tw[m] = make_float2(c, s);
  }
  // float4 vector loads (16B/lane), scatter at base-4 digit-reversed positions
  {
    const float4 qv = ((const float4*)qs)[tid];
    const float4 kv = ((const float4*)ks)[tid];
#pragma unroll
    for (int j = 0; j < 4; ++j) {
      const int n = 4 * tid + j;
      const int r4 = ((n & 3) << 8) | (((n >> 2) & 3) << 6) | (((n >> 4) & 3) << 4)
                   | (((n >> 6) & 3) << 2) | ((n >> 8) & 3);
      data[PADI(r4)] = make_float2(((const float*)&qv)[j], ((const float*)&kv)[j]);
    }
  }
  __syncthreads();

  int quarter = 1, step = 256;
  for (int s = 0; s < 5; ++s) {
    const int j = tid & (quarter - 1);
    const int pos = 4 * tid - 3 * j;
    const float2 x0 = data[PADI(pos)];
    const float2 x1 = data[PADI(pos + quarter)];
    const float2 x2 = data[PADI(pos + 2 * quarter)];
    const float2 x3 = data[PADI(pos + 3 * quarter)];
    const int e1 = j * step;
    const float2 a1 = cmul(x1, tw[e1]);
    const float2 a2 = cmul(x2, tw[2 * e1]);
    const float2 a3 = cmul(x3, tw[3 * e1]);
    const float2 t0 = make_float2(x0.x + a2.x, x0.y + a2.y);
    const float2 t1 = make_float2(x0.x - a2.x, x0.y - a2.y);
    const float2 t2 = make_float2(a1.x + a3.x, a1.y + a3.y);
    const float2 t3 = make_float2(a1.x - a3.x, a1.y - a3.y);
    data[PADI(pos)]               = make_float2(t0.x + t2.x, t0.y + t2.y);
    data[PADI(pos + quarter)]     = make_float2(t1.x + t3.y, t1.y - t3.x);
    data[PADI(pos + 2 * quarter)] = make_float2(t0.x - t2.x, t0.y - t2.y);
    data[PADI(pos + 3 * quarter)] = make_float2(t1.x - t3.y, t1.y + t3.x);
    __syncthreads();
    quarter <<= 2; step >>= 2;
  }

  // untangle + normalize. Layout: fq[f] = cos_f (f 0..512); fq[512+f] = sin_f
  // (f 1..511). sin_0 = sin_512 = 0 exactly (real bins) -> dropped.
  for (int f = tid; f <= 512; f += 256) {
    const float2 z1 = data[PADI(f)];
    const float2 z2 = data[PADI((1024 - f) & 1023)];
    const float qr = z1.x + z2.x, qi = z1.y - z2.y;
    const float kr = z1.y + z2.y, ki = z2.x - z1.x;
    float qc, qsn, kc, ksn;
    const float qm2 = qr * qr + qi * qi;
    if (qm2 > 1e-30f) { const float iv = rsqrtf(qm2); qc = qr * iv; qsn = qi * iv; }
    else              { qc = 1.0f; qsn = 0.0f; }
    const float km2 = kr * kr + ki * ki;
    if (km2 > 1e-30f) { const float iv = rsqrtf(km2); kc = kr * iv; ksn = ki * iv; }
    else              { kc = 1.0f; ksn = 0.0f; }
    fq[f] = __float2bfloat16(qc);
    fk[f] = __float2bfloat16(kc);
    if (f > 0 && f < 512) {
      fq[512 + f] = __float2bfloat16(qsn);
      fk[512 + f] = __float2bfloat16(ksn);
    }
  }
}

// ---------------------------------------------------------------------------
// Kernel 2: V [B,S,H] fp32 -> Vt [B,H,S] bf16
// ---------------------------------------------------------------------------
__global__ __launch_bounds__(256) void vt_kernel(
    const float* __restrict__ V, __hip_bfloat16* __restrict__ Vt) {
  const int b = blockIdx.z;
  const int h0 = blockIdx.x * 32;
  const int s0 = blockIdx.y * 32;
  __shared__ float t[32][33];
  const int tid = threadIdx.x;
  const int c = tid & 31;
  const int r8 = tid >> 5;
  const float* Vb = V + (size_t)b * Ss * Hh;
#pragma unroll
  for (int e = 0; e < 4; ++e) {
    const int r = r8 + e * 8;
    t[r][c] = Vb[(size_t)(s0 + r) * Hh + h0 + c];
  }
  __syncthreads();
  __hip_bfloat16* O = Vt + (size_t)b * Hh * Ss;
#pragma unroll
  for (int e = 0; e < 4; ++e) {
    const int hh = r8 + e * 8;
    O[(size_t)(h0 + hh) * Ss + s0 + c] = __float2bfloat16(t[c][hh]);
  }
}

// ---------------------------------------------------------------------------
// bf16 MFMA GEMM (32x32x16), C = A*B^T, 256x256 tile, BK=64, 8 waves,
// 2 phases/K-tile, deep counted vmcnt (round-9 proven structure).
// ROUND-13: staged-traffic roofline analysis (both GEMMs sit at ~6.3 TB/s
// composite memory supply; FETCH_SIZE only showed the HBM slice, the rest
// came from L3). 256x256 minimizes (BM+BN)/(BM*BN) staged bytes per FLOP;
// PV moves from 128x256 (Vt staged 16x, 403 MB) to 256x256 (8x, 268 MB).
// LDS layout per buffer: [rg][kc][512 shorts] 1KB subtiles; linear
// global_load_lds lane write == ds_read order == MFMA operand order
// (row=lane&31, k8=lane>>5) -> conflict-free, swizzle-free.
// C/D layout [m74/m101]: col=lane&31, row=(reg&3)+8*(reg>>2)+4*(lane>>5).
// EPI 0: C = acc/513 (scores; +1 dropped, softmax shift-invariant).
// EPI 1: C = acc (PV).
// ---------------------------------------------------------------------------
template<int K, int LDA, int LDB, int LDC, int EPI>
__global__ __launch_bounds__(512, 2) void gemm32(
    const __hip_bfloat16* __restrict__ Ag, const __hip_bfloat16* __restrict__ Bg,
    float* __restrict__ Cg, size_t strA, size_t strB, size_t strC) {
  constexpr int nt = K / 64;
  constexpr int MF = 4;           // m-frags per wave (4 x 32 = 128 rows)

  // bijective XCD swizzle (nwg % 8 == 0)
  const int gx = gridDim.x, gy = gridDim.y;
  const int nwg = gx * gy * (int)gridDim.z;
  int f = ((int)blockIdx.z * gy + (int)blockIdx.y) * gx + (int)blockIdx.x;
  f = (f & 7) * (nwg >> 3) + (f >> 3);
  const int bx = f % gx; f /= gx;
  const int by = f % gy;
  const int bz = f / gy;

  const int i0 = by * 256;
  const int j0 = bx * 256;
  const char* Ab = (const char*)(Ag + (size_t)bz * strA);
  const char* Bp = (const char*)(Bg + (size_t)bz * strB);
  float* C = Cg + (size_t)bz * strC;

  __shared__ short As[2][16384];   // [rg 0..7][kc 0..3][512]  2 x 32KB
  __shared__ short Bs[2][16384];   // 128KB total

  const int tid = threadIdx.x;
  const int lane = tid & 63;
  const int w  = tid >> 6;        // wave 0..7
  const int wm = w >> 2;          // 0..1 (M: 128 rows each)
  const int wn = w & 3;           // 0..3 (N: 64 cols each)

  f32x16 acc[MF][2];
#pragma unroll
  for (int mi = 0; mi < MF; ++mi)
#pragma unroll
    for (int ni = 0; ni < 2; ++ni)
#pragma unroll
      for (int r = 0; r < 16; ++r) acc[mi][ni][r] = 0.0f;

#define BAR() __builtin_amdgcn_s_barrier()
  // deep wait: 2 chunk-pairs in flight = 8 loads (A:2 + B:2 per wave each)
#define WAITDEEP() asm volatile("s_waitcnt vmcnt(8)")

  // stage A/B chunk (khalf kh) of K-tile tt into buffer dd: 2 loads/thread
#define SA(dd, tt, kh)                                                                   \
  do {                                                                                   \
    _Pragma("unroll")                                                                    \
    for (int ii = 0; ii < 2; ++ii) {                                                     \
      const int f_ = w * 2 + ii;                                                         \
      const int rg_ = f_ >> 1;                                                           \
      const int kc_ = 2 * (kh) + (f_ & 1);                                               \
      __builtin_amdgcn_global_load_lds(                                                  \
          (GVoid*)(Ab + (size_t)(i0 + rg_ * 32 + (lane & 31)) * (LDA * 2) +              \
                   (size_t)(tt) * 128 + kc_ * 32 + (lane >> 5) * 16),                    \
          (LVoid*)&As[dd][(rg_ * 4 + kc_) * 512], 16, 0, 0);                             \
    }                                                                                    \
  } while (0)
#define SB(dd, tt, kh)                                                                   \
  do {                                                                                   \
    _Pragma("unroll")                                                                    \
    for (int ii = 0; ii < 2; ++ii) {                                                     \
      const int f_ = w * 2 + ii;                                                         \
      const int rg_ = f_ >> 1;                                                           \
      const int kc_ = 2 * (kh) + (f_ & 1);                                               \
      __builtin_amdgcn_global_load_lds(                                                  \
          (GVoid*)(Bp + (size_t)(j0 + rg_ * 32 + (lane & 31)) * (LDB * 2) +              \
                   (size_t)(tt) * 128 + kc_ * 32 + (lane >> 5) * 16),                    \
          (LVoid*)&Bs[dd][(rg_ * 4 + kc_) * 512], 16, 0, 0);                             \
    }                                                                                    \
  } while (0)
#define RA(dd, kh)                                                                       \
  _Pragma("unroll")                                                                      \
  for (int mi = 0; mi < MF; ++mi)                                                        \
    _Pragma("unroll")                                                                    \
    for (int kb = 0; kb < 2; ++kb)                                                       \
      af[mi][kb] = lds_read_b128(                                                        \
          &As[dd][((wm * MF + mi) * 4 + 2 * (kh) + kb) * 512 + lane * 8]);
#define RB(dd, kh)                                                                       \
  _Pragma("unroll")                                                                      \
  for (int ni = 0; ni < 2; ++ni)                                                         \
    _Pragma("unroll")                                                                    \
    for (int kb = 0; kb < 2; ++kb)                                                       \
      bf[ni][kb] = lds_read_b128(                                                        \
          &Bs[dd][((wn * 2 + ni) * 4 + 2 * (kh) + kb) * 512 + lane * 8]);
#define MM()                                                                             \
  asm volatile("s_waitcnt lgkmcnt(0)");                                                  \
  __builtin_amdgcn_sched_barrier(0);                                                     \
  __builtin_amdgcn_s_setprio(1);                                                         \
  _Pragma("unroll")                                                                      \
  for (int mi = 0; mi < MF; ++mi)                                                        \
    _Pragma("unroll")                                                                    \
    for (int ni = 0; ni < 2; ++ni)                                                       \
      _Pragma("unroll")                                                                  \
      for (int kb = 0; kb < 2; ++kb)                                                     \
        acc[mi][ni] = __builtin_amdgcn_mfma_f32_32x32x16_bf16(                           \
            af[mi][kb], bf[ni][kb], acc[mi][ni], 0, 0, 0);                               \
  __builtin_amdgcn_s_setprio(0);                                                         \
  __builtin_amdgcn_sched_barrier(0);

  // prologue: (0,kh0), (0,kh1), (1,kh0); deep wait guarantees (0,kh0)
  SA(0, 0, 0); SB(0, 0, 0);
  SA(0, 0, 1); SB(0, 0, 1);
  SA(1, 1, 0); SB(1, 1, 0);
  WAITDEEP();
  BAR();

  for (int t = 0; t < nt; ++t) {
    const int d = t & 1;
    bf16x8 af[MF][2], bf[2][2];

    // ---- phase 0: k-half 0
    RA(d, 0); RB(d, 0);
    if (t + 1 < nt) { SA(d ^ 1, t + 1, 1); SB(d ^ 1, t + 1, 1); }
    MM();
    if (t + 2 < nt) WAITDEEP();
    else            asm volatile("s_waitcnt vmcnt(0)");
    BAR();

    // ---- phase 1: k-half 1
    RA(d, 1); RB(d, 1);
    if (t + 2 < nt) { SA(d, t + 2, 0); SB(d, t + 2, 0); }
    MM();
    if (t + 2 < nt) WAITDEEP();
    else            asm volatile("s_waitcnt vmcnt(0)");
    BAR();
  }
#undef SA
#undef SB
#undef RA
#undef RB
#undef MM
#undef WAITDEEP
#undef BAR

  // epilogue: 32x32 C/D layout [m74/m101]
  const int col = lane & 31;
  const int rbase = (lane >> 5) * 4;
#pragma unroll
  for (int mi = 0; mi < MF; ++mi) {
#pragma unroll
    for (int ni = 0; ni < 2; ++ni) {
#pragma unroll
      for (int r = 0; r < 16; ++r) {
        const int row = (r & 3) + 8 * (r >> 2) + rbase;
        const int i = i0 + wm * 128 + mi * 32 + row;
        const int j = j0 + wn * 64 + ni * 32 + col;
        float v = acc[mi][ni][r];
        if (EPI == 0) v *= (1.0f / 513.0f);
        C[(size_t)i * LDC + j] = v;
      }
    }
  }
}

// ---------------------------------------------------------------------------
// Kernel 3: in-place row softmax + bf16 copy for PV GEMM.
// ---------------------------------------------------------------------------
__global__ __launch_bounds__(256) void softmax_kernel(
    float* __restrict__ W, __hip_bfloat16* __restrict__ Wb) {
  const size_t row = blockIdx.x;
  float* p = W + row * (size_t)Ss;
  __hip_bfloat16* pb = Wb + row * (size_t)Ss;
  const int tid = threadIdx.x;
  __shared__ float red[4];

  const float4* p4 = (const float4*)p;
  const float4 a = p4[2 * tid];
  const float4 bq = p4[2 * tid + 1];
  float v[8] = {a.x, a.y, a.z, a.w, bq.x, bq.y, bq.z, bq.w};

  float m = v[0];
#pragma unroll
  for (int e = 1; e < 8; ++e) m = fmaxf(m, v[e]);
#pragma unroll
  for (int off = 32; off > 0; off >>= 1) m = fmaxf(m, __shfl_xor(m, off, 64));
  if ((tid & 63) == 0) red[tid >> 6] = m;
  __syncthreads();
  m = fmaxf(fmaxf(red[0], red[1]), fmaxf(red[2], red[3]));

  float sum = 0.0f;
#pragma unroll
  for (int e = 0; e < 8; ++e) { v[e] = __expf(v[e] - m); sum += v[e]; }
#pragma unroll
  for (int off = 32; off > 0; off >>= 1) sum += __shfl_xor(sum, off, 64);
  __syncthreads();
  if ((tid & 63) == 0) red[tid >> 6] = sum;
  __syncthreads();
  sum = red[0] + red[1] + red[2] + red[3];

  const float rs = 1.0f / sum;
#pragma unroll
  for (int e = 0; e < 8; ++e) v[e] *= rs;

  float4* o4 = (float4*)p;
  o4[2 * tid]     = make_float4(v[0], v[1], v[2], v[3]);
  o4[2 * tid + 1] = make_float4(v[4], v[5], v[6], v[7]);

  bf16x8 ob;
#pragma unroll
  for (int e = 0; e < 8; ++e) ob[e] = (short)bf16bits(v[e]);
  *(bf16x8*)&pb[8 * tid] = ob;
}

// ---------------------------------------------------------------------------
extern "C" void kernel_launch(void* const* d_in, const int* in_sizes, int n_in,
                              void* d_out, int out_size, void* d_ws, size_t ws_size,
                              hipStream_t stream) {
  const float* Q = (const float*)d_in[0];
  const float* K = (const float*)d_in[1];
  const float* V = (const float*)d_in[2];

  float* out     = (float*)d_out;                       // [B,S,H]
  float* weights = out + (size_t)Bb * Ss * Hh;          // [B,S,S]

  __hip_bfloat16* FQb = (__hip_bfloat16*)d_ws;          // [B,S,1024] bf16
  __hip_bfloat16* FKb = FQb + (size_t)Bb * Ss * KP2;
  __hip_bfloat16* Vtb = FKb + (size_t)Bb * Ss * KP2;    // [B,H,S] bf16
  __hip_bfloat16* Wb  = (__hip_bfloat16*)d_ws;          // aliases dead FQb/FKb

  hipLaunchKernelGGL(fft_phase_kernel, dim3(Bb * Ss), dim3(256), 0, stream,
                     Q, K, FQb, FKb);
  hipLaunchKernelGGL(vt_kernel, dim3(Hh / 32, Ss / 32, Bb), dim3(256), 0, stream,
                     V, Vtb);
  // score: 256x256 tiles, K=1024, grid 8x8x4 = 256 WGs
  hipLaunchKernelGGL((gemm32<KP2, KP2, KP2, Ss, 0>), dim3(Ss / 256, Ss / 256, Bb),
                     dim3(512), 0, stream, FQb, FKb, weights,
                     (size_t)Ss * KP2, (size_t)Ss * KP2, (size_t)Ss * Ss);
  hipLaunchKernelGGL(softmax_kernel, dim3(Bb * Ss), dim3(256), 0, stream,
                     weights, Wb);
  // PV: 256x256 tiles, K=2048, grid 4x8x4 = 128 WGs (traffic 403->268 MB)
  hipLaunchKernelGGL((gemm32<Ss, Ss, Ss, Hh, 1>), dim3(Hh / 256, Ss / 256, Bb),
                     dim3(512), 0, stream, Wb, Vtb, out,
                     (size_t)Ss * Ss, (size_t)Hh * Ss, (size_t)Ss * Hh);
}

// Round 14
// 165.223 us; speedup vs baseline: 1.2396x; 1.0943x over previous
//
#include <hip/hip_runtime.h>
#include <hip/hip_bf16.h>
#include <math.h>

// Problem constants
#define Bb 4
#define Ss 2048
#define Hh 1024
#define Ff 513           // H/2 + 1 rfft bins
#define KP2 1024         // feature K: cos[0..512] ++ sin[1..511] (sin0,sin512==0 exactly)

typedef __attribute__((ext_vector_type(8))) short bf16x8;
typedef __attribute__((ext_vector_type(16))) float f32x16;

typedef const __attribute__((address_space(1))) void GVoid;
typedef __attribute__((address_space(3))) void LVoid;

#define PADI(i) ((i) + ((i) >> 4))

__device__ __forceinline__ float2 cmul(float2 a, float2 b) {
  return make_float2(a.x * b.x - a.y * b.y, a.x * b.y + a.y * b.x);
}

__device__ __forceinline__ unsigned short bf16bits(float x) {
  __hip_bfloat16 h = __float2bfloat16(x);
  return *reinterpret_cast<unsigned short*>(&h);
}

// Inline-asm LDS read (round-6 win: opaque to compiler waitcnt insertion).
__device__ __forceinline__ bf16x8 lds_read_b128(const short* p) {
  bf16x8 r;
  asm volatile("ds_read_b128 %0, %1"
               : "=&v"(r)
               : "v"((const __attribute__((address_space(3))) short*)p));
  return r;
}

// ---------------------------------------------------------------------------
// Kernel 1: packed-real FFT (radix-4, z = Q + iK), untangle, unit-normalize,
// emit bf16 features [cos 0..512 | sin 1..511] (1024 dims exactly).
// ---------------------------------------------------------------------------
__global__ __launch_bounds__(256) void fft_phase_kernel(
    const float* __restrict__ Q, const float* __restrict__ Kin,
    __hip_bfloat16* __restrict__ FQ, __hip_bfloat16* __restrict__ FK) {
  const int row = blockIdx.x;
  const float* qs = Q   + (size_t)row * Hh;
  const float* ks = Kin + (size_t)row * Hh;
  __hip_bfloat16* fq = FQ + (size_t)row * KP2;
  __hip_bfloat16* fk = FK + (size_t)row * KP2;

  __shared__ float2 data[PADI(1023) + 1];
  __shared__ float2 tw[1024];
  const int tid = threadIdx.x;

#pragma unroll
  for (int e = 0; e < 4; ++e) {
    const int m = tid + e * 256;
    float s, c;
    sincosf(-6.283185307179586f * (float)m * (1.0f / 1024.0f), &s, &c);
    tw[m] = make_float2(c, s);
  }
  {
    const float4 qv = ((const float4*)qs)[tid];
    const float4 kv = ((const float4*)ks)[tid];
#pragma unroll
    for (int j = 0; j < 4; ++j) {
      const int n = 4 * tid + j;
      const int r4 = ((n & 3) << 8) | (((n >> 2) & 3) << 6) | (((n >> 4) & 3) << 4)
                   | (((n >> 6) & 3) << 2) | ((n >> 8) & 3);
      data[PADI(r4)] = make_float2(((const float*)&qv)[j], ((const float*)&kv)[j]);
    }
  }
  __syncthreads();

  int quarter = 1, step = 256;
  for (int s = 0; s < 5; ++s) {
    const int j = tid & (quarter - 1);
    const int pos = 4 * tid - 3 * j;
    const float2 x0 = data[PADI(pos)];
    const float2 x1 = data[PADI(pos + quarter)];
    const float2 x2 = data[PADI(pos + 2 * quarter)];
    const float2 x3 = data[PADI(pos + 3 * quarter)];
    const int e1 = j * step;
    const float2 a1 = cmul(x1, tw[e1]);
    const float2 a2 = cmul(x2, tw[2 * e1]);
    const float2 a3 = cmul(x3, tw[3 * e1]);
    const float2 t0 = make_float2(x0.x + a2.x, x0.y + a2.y);
    const float2 t1 = make_float2(x0.x - a2.x, x0.y - a2.y);
    const float2 t2 = make_float2(a1.x + a3.x, a1.y + a3.y);
    const float2 t3 = make_float2(a1.x - a3.x, a1.y - a3.y);
    data[PADI(pos)]               = make_float2(t0.x + t2.x, t0.y + t2.y);
    data[PADI(pos + quarter)]     = make_float2(t1.x + t3.y, t1.y - t3.x);
    data[PADI(pos + 2 * quarter)] = make_float2(t0.x - t2.x, t0.y - t2.y);
    data[PADI(pos + 3 * quarter)] = make_float2(t1.x - t3.y, t1.y + t3.x);
    __syncthreads();
    quarter <<= 2; step >>= 2;
  }

  for (int f = tid; f <= 512; f += 256) {
    const float2 z1 = data[PADI(f)];
    const float2 z2 = data[PADI((1024 - f) & 1023)];
    const float qr = z1.x + z2.x, qi = z1.y - z2.y;
    const float kr = z1.y + z2.y, ki = z2.x - z1.x;
    float qc, qsn, kc, ksn;
    const float qm2 = qr * qr + qi * qi;
    if (qm2 > 1e-30f) { const float iv = rsqrtf(qm2); qc = qr * iv; qsn = qi * iv; }
    else              { qc = 1.0f; qsn = 0.0f; }
    const float km2 = kr * kr + ki * ki;
    if (km2 > 1e-30f) { const float iv = rsqrtf(km2); kc = kr * iv; ksn = ki * iv; }
    else              { kc = 1.0f; ksn = 0.0f; }
    fq[f] = __float2bfloat16(qc);
    fk[f] = __float2bfloat16(kc);
    if (f > 0 && f < 512) {
      fq[512 + f] = __float2bfloat16(qsn);
      fk[512 + f] = __float2bfloat16(ksn);
    }
  }
}

// ---------------------------------------------------------------------------
// Kernel 2: V [B,S,H] fp32 -> Vt [B,H,S] bf16
// ---------------------------------------------------------------------------
__global__ __launch_bounds__(256) void vt_kernel(
    const float* __restrict__ V, __hip_bfloat16* __restrict__ Vt) {
  const int b = blockIdx.z;
  const int h0 = blockIdx.x * 32;
  const int s0 = blockIdx.y * 32;
  __shared__ float t[32][33];
  const int tid = threadIdx.x;
  const int c = tid & 31;
  const int r8 = tid >> 5;
  const float* Vb = V + (size_t)b * Ss * Hh;
#pragma unroll
  for (int e = 0; e < 4; ++e) {
    const int r = r8 + e * 8;
    t[r][c] = Vb[(size_t)(s0 + r) * Hh + h0 + c];
  }
  __syncthreads();
  __hip_bfloat16* O = Vt + (size_t)b * Hh * Ss;
#pragma unroll
  for (int e = 0; e < 4; ++e) {
    const int hh = r8 + e * 8;
    O[(size_t)(h0 + hh) * Ss + s0 + c] = __float2bfloat16(t[c][hh]);
  }
}

// ---------------------------------------------------------------------------
// bf16 MFMA GEMM (32x32x16), C = A*B^T, BMT x 256 tile, BK=64, 8 waves,
// 2 phases/K-tile, deep counted vmcnt. ROUND-14: consolidation — both GEMM
// dispatches at their measured staging-traffic roofline configs:
//   score: BMT=256 (268 MB staged = 42.5 us floor), grid 8x8x4 = 256 WGs
//   PV:    BMT=128 (402 MB staged = 64 us floor),  grid 4x16x4 = 256 WGs
// (r13's PV-256^2 cut traffic but halved the active CUs -> regressed.)
// LDS layout per buffer: [rg][kc][512 shorts] 1KB subtiles; linear
// global_load_lds lane write == ds_read order == MFMA operand order
// (row=lane&31, k8=lane>>5) -> conflict-free, swizzle-free.
// C/D layout [m74/m101]: col=lane&31, row=(reg&3)+8*(reg>>2)+4*(lane>>5).
// EPI 0: C = acc/513 (scores). EPI 1: C = acc (PV).
// ---------------------------------------------------------------------------
template<int K, int LDA, int LDB, int LDC, int EPI, int BMT>
__global__ __launch_bounds__(512, 2) void gemm32(
    const __hip_bfloat16* __restrict__ Ag, const __hip_bfloat16* __restrict__ Bg,
    float* __restrict__ Cg, size_t strA, size_t strB, size_t strC) {
  constexpr int nt  = K / 64;
  constexpr int MF  = BMT / 64;   // m-frags per wave (score 4, PV 2)
  constexpr int SAW = BMT / 128;  // SA loads per thread per kh chunk (2, 1)

  // bijective XCD swizzle (nwg % 8 == 0)
  const int gx = gridDim.x, gy = gridDim.y;
  const int nwg = gx * gy * (int)gridDim.z;
  int f = ((int)blockIdx.z * gy + (int)blockIdx.y) * gx + (int)blockIdx.x;
  f = (f & 7) * (nwg >> 3) + (f >> 3);
  const int bx = f % gx; f /= gx;
  const int by = f % gy;
  const int bz = f / gy;

  const int i0 = by * BMT;
  const int j0 = bx * 256;
  const char* Ab = (const char*)(Ag + (size_t)bz * strA);
  const char* Bp = (const char*)(Bg + (size_t)bz * strB);
  float* C = Cg + (size_t)bz * strC;

  __shared__ short As[2][BMT * 64];
  __shared__ short Bs[2][256 * 64];

  const int tid = threadIdx.x;
  const int lane = tid & 63;
  const int w  = tid >> 6;
  const int wm = w >> 2;
  const int wn = w & 3;

  f32x16 acc[MF][2];
#pragma unroll
  for (int mi = 0; mi < MF; ++mi)
#pragma unroll
    for (int ni = 0; ni < 2; ++ni)
#pragma unroll
      for (int r = 0; r < 16; ++r) acc[mi][ni][r] = 0.0f;

#define BAR() __builtin_amdgcn_s_barrier()
  // deep wait: 2 chunk-pairs in flight; loads/chunk-pair = SAW + 2
#define WAITDEEP()                                                                       \
  do {                                                                                   \
    if constexpr (SAW == 2) asm volatile("s_waitcnt vmcnt(8)");                          \
    else                    asm volatile("s_waitcnt vmcnt(6)");                          \
  } while (0)

#define SA(dd, tt, kh)                                                                   \
  do {                                                                                   \
    _Pragma("unroll")                                                                    \
    for (int ii = 0; ii < SAW; ++ii) {                                                   \
      const int f_ = w * SAW + ii;                                                       \
      const int rg_ = f_ >> 1;                                                           \
      const int kc_ = 2 * (kh) + (f_ & 1);                                               \
      __builtin_amdgcn_global_load_lds(                                                  \
          (GVoid*)(Ab + (size_t)(i0 + rg_ * 32 + (lane & 31)) * (LDA * 2) +              \
                   (size_t)(tt) * 128 + kc_ * 32 + (lane >> 5) * 16),                    \
          (LVoid*)&As[dd][(rg_ * 4 + kc_) * 512], 16, 0, 0);                             \
    }                                                                                    \
  } while (0)
#define SB(dd, tt, kh)                                                                   \
  do {                                                                                   \
    _Pragma("unroll")                                                                    \
    for (int ii = 0; ii < 2; ++ii) {                                                     \
      const int f_ = w * 2 + ii;                                                         \
      const int rg_ = f_ >> 1;                                                           \
      const int kc_ = 2 * (kh) + (f_ & 1);                                               \
      __builtin_amdgcn_global_load_lds(                                                  \
          (GVoid*)(Bp + (size_t)(j0 + rg_ * 32 + (lane & 31)) * (LDB * 2) +              \
                   (size_t)(tt) * 128 + kc_ * 32 + (lane >> 5) * 16),                    \
          (LVoid*)&Bs[dd][(rg_ * 4 + kc_) * 512], 16, 0, 0);                             \
    }                                                                                    \
  } while (0)
#define RA(dd, kh)                                                                       \
  _Pragma("unroll")                                                                      \
  for (int mi = 0; mi < MF; ++mi)                                                        \
    _Pragma("unroll")                                                                    \
    for (int kb = 0; kb < 2; ++kb)                                                       \
      af[mi][kb] = lds_read_b128(                                                        \
          &As[dd][((wm * MF + mi) * 4 + 2 * (kh) + kb) * 512 + lane * 8]);
#define RB(dd, kh)                                                                       \
  _Pragma("unroll")                                                                      \
  for (int ni = 0; ni < 2; ++ni)                                                         \
    _Pragma("unroll")                                                                    \
    for (int kb = 0; kb < 2; ++kb)                                                       \
      bf[ni][kb] = lds_read_b128(                                                        \
          &Bs[dd][((wn * 2 + ni) * 4 + 2 * (kh) + kb) * 512 + lane * 8]);
#define MM()                                                                             \
  asm volatile("s_waitcnt lgkmcnt(0)");                                                  \
  __builtin_amdgcn_sched_barrier(0);                                                     \
  __builtin_amdgcn_s_setprio(1);                                                         \
  _Pragma("unroll")                                                                      \
  for (int mi = 0; mi < MF; ++mi)                                                        \
    _Pragma("unroll")                                                                    \
    for (int ni = 0; ni < 2; ++ni)                                                       \
      _Pragma("unroll")                                                                  \
      for (int kb = 0; kb < 2; ++kb)                                                     \
        acc[mi][ni] = __builtin_amdgcn_mfma_f32_32x32x16_bf16(                           \
            af[mi][kb], bf[ni][kb], acc[mi][ni], 0, 0, 0);                               \
  __builtin_amdgcn_s_setprio(0);                                                         \
  __builtin_amdgcn_sched_barrier(0);

  // prologue: (0,kh0), (0,kh1), (1,kh0); deep wait guarantees (0,kh0)
  SA(0, 0, 0); SB(0, 0, 0);
  SA(0, 0, 1); SB(0, 0, 1);
  SA(1, 1, 0); SB(1, 1, 0);
  WAITDEEP();
  BAR();

  for (int t = 0; t < nt; ++t) {
    const int d = t & 1;
    bf16x8 af[MF][2], bf[2][2];

    // ---- phase 0: k-half 0
    RA(d, 0); RB(d, 0);
    if (t + 1 < nt) { SA(d ^ 1, t + 1, 1); SB(d ^ 1, t + 1, 1); }
    MM();
    if (t + 2 < nt) WAITDEEP();
    else            asm volatile("s_waitcnt vmcnt(0)");
    BAR();

    // ---- phase 1: k-half 1
    RA(d, 1); RB(d, 1);
    if (t + 2 < nt) { SA(d, t + 2, 0); SB(d, t + 2, 0); }
    MM();
    if (t + 2 < nt) WAITDEEP();
    else            asm volatile("s_waitcnt vmcnt(0)");
    BAR();
  }
#undef SA
#undef SB
#undef RA
#undef RB
#undef MM
#undef WAITDEEP
#undef BAR

  // epilogue: 32x32 C/D layout [m74/m101]
  const int col = lane & 31;
  const int rbase = (lane >> 5) * 4;
#pragma unroll
  for (int mi = 0; mi < MF; ++mi) {
#pragma unroll
    for (int ni = 0; ni < 2; ++ni) {
#pragma unroll
      for (int r = 0; r < 16; ++r) {
        const int row = (r & 3) + 8 * (r >> 2) + rbase;
        const int i = i0 + wm * (MF * 32) + mi * 32 + row;
        const int j = j0 + wn * 64 + ni * 32 + col;
        float v = acc[mi][ni][r];
        if (EPI == 0) v *= (1.0f / 513.0f);
        C[(size_t)i * LDC + j] = v;
      }
    }
  }
}

// ---------------------------------------------------------------------------
// Kernel 3: in-place row softmax + bf16 copy for PV GEMM.
// ---------------------------------------------------------------------------
__global__ __launch_bounds__(256) void softmax_kernel(
    float* __restrict__ W, __hip_bfloat16* __restrict__ Wb) {
  const size_t row = blockIdx.x;
  float* p = W + row * (size_t)Ss;
  __hip_bfloat16* pb = Wb + row * (size_t)Ss;
  const int tid = threadIdx.x;
  __shared__ float red[4];

  const float4* p4 = (const float4*)p;
  const float4 a = p4[2 * tid];
  const float4 bq = p4[2 * tid + 1];
  float v[8] = {a.x, a.y, a.z, a.w, bq.x, bq.y, bq.z, bq.w};

  float m = v[0];
#pragma unroll
  for (int e = 1; e < 8; ++e) m = fmaxf(m, v[e]);
#pragma unroll
  for (int off = 32; off > 0; off >>= 1) m = fmaxf(m, __shfl_xor(m, off, 64));
  if ((tid & 63) == 0) red[tid >> 6] = m;
  __syncthreads();
  m = fmaxf(fmaxf(red[0], red[1]), fmaxf(red[2], red[3]));

  float sum = 0.0f;
#pragma unroll
  for (int e = 0; e < 8; ++e) { v[e] = __expf(v[e] - m); sum += v[e]; }
#pragma unroll
  for (int off = 32; off > 0; off >>= 1) sum += __shfl_xor(sum, off, 64);
  __syncthreads();
  if ((tid & 63) == 0) red[tid >> 6] = sum;
  __syncthreads();
  sum = red[0] + red[1] + red[2] + red[3];

  const float rs = 1.0f / sum;
#pragma unroll
  for (int e = 0; e < 8; ++e) v[e] *= rs;

  float4* o4 = (float4*)p;
  o4[2 * tid]     = make_float4(v[0], v[1], v[2], v[3]);
  o4[2 * tid + 1] = make_float4(v[4], v[5], v[6], v[7]);

  bf16x8 ob;
#pragma unroll
  for (int e = 0; e < 8; ++e) ob[e] = (short)bf16bits(v[e]);
  *(bf16x8*)&pb[8 * tid] = ob;
}

// ---------------------------------------------------------------------------
extern "C" void kernel_launch(void* const* d_in, const int* in_sizes, int n_in,
                              void* d_out, int out_size, void* d_ws, size_t ws_size,
                              hipStream_t stream) {
  const float* Q = (const float*)d_in[0];
  const float* K = (const float*)d_in[1];
  const float* V = (const float*)d_in[2];

  float* out     = (float*)d_out;                       // [B,S,H]
  float* weights = out + (size_t)Bb * Ss * Hh;          // [B,S,S]

  __hip_bfloat16* FQb = (__hip_bfloat16*)d_ws;          // [B,S,1024] bf16
  __hip_bfloat16* FKb = FQb + (size_t)Bb * Ss * KP2;
  __hip_bfloat16* Vtb = FKb + (size_t)Bb * Ss * KP2;    // [B,H,S] bf16
  __hip_bfloat16* Wb  = (__hip_bfloat16*)d_ws;          // aliases dead FQb/FKb

  hipLaunchKernelGGL(fft_phase_kernel, dim3(Bb * Ss), dim3(256), 0, stream,
                     Q, K, FQb, FKb);
  hipLaunchKernelGGL(vt_kernel, dim3(Hh / 32, Ss / 32, Bb), dim3(256), 0, stream,
                     V, Vtb);
  // score: 256x256 tiles, K=1024, grid 8x8x4 = 256 WGs (staging roofline)
  hipLaunchKernelGGL((gemm32<KP2, KP2, KP2, Ss, 0, 256>),
                     dim3(Ss / 256, Ss / 256, Bb), dim3(512), 0, stream,
                     FQb, FKb, weights,
                     (size_t)Ss * KP2, (size_t)Ss * KP2, (size_t)Ss * Ss);
  hipLaunchKernelGGL(softmax_kernel, dim3(Bb * Ss), dim3(256), 0, stream,
                     weights, Wb);
  // PV: 128x256 tiles, grid 4x16x4 = 256 WGs (r9 measured-best config)
  hipLaunchKernelGGL((gemm32<Ss, Ss, Ss, Hh, 1, 128>),
                     dim3(Hh / 256, Ss / 128, Bb), dim3(512), 0, stream,
                     Wb, Vtb, out,
                     (size_t)Ss * Ss, (size_t)Hh * Ss, (size_t)Ss * Hh);
}